// Round 7
// baseline (123.545 us; speedup 1.0000x reference)
//
#include <hip/hip_runtime.h>
#include <hip/hip_bf16.h>
#include <math.h>

#define D 256
#define INV_TAU 20.0f
#define CAP 64
#define PBUF 384
#define NSPLIT 16

typedef __attribute__((ext_vector_type(4))) float f32x4;
typedef __attribute__((ext_vector_type(8))) short bf16x8_t;

#define GLOAD16(gp, lp) \
    __builtin_amdgcn_global_load_lds((const __attribute__((address_space(1))) void*)(gp), \
                                     (__attribute__((address_space(3))) void*)(lp), 16, 0, 0)

__device__ __forceinline__ unsigned short f2bf(float f) {
    union { float f; unsigned u; } v; v.f = f;
    unsigned r = v.u + 0x7FFFu + ((v.u >> 16) & 1u);
    return (unsigned short)(r >> 16);
}

// Fused: L2-normalize every row of que/sen/sec into bf16. Wave per row.
__global__ void norm_all(const float* __restrict__ que, const float* __restrict__ sen,
                         const float* __restrict__ sec,
                         unsigned short* __restrict__ queb, unsigned short* __restrict__ senb,
                         unsigned short* __restrict__ secb, int Q, int N, int S) {
    int r = blockIdx.x * 4 + (threadIdx.x >> 6);
    int lane = threadIdx.x & 63;
    if (r >= Q + N + S) return;
    const float* src; unsigned short* dst; int row;
    if (r < Q) { src = que; dst = queb; row = r; }
    else if (r < Q + N) { src = sen; dst = senb; row = r - Q; }
    else { src = sec; dst = secb; row = r - Q - N; }
    const float4* p = (const float4*)(src + (size_t)row * D);
    float4 v = p[lane];
    float ss = v.x * v.x + v.y * v.y + v.z * v.z + v.w * v.w;
    #pragma unroll
    for (int m = 1; m < 64; m <<= 1) ss += __shfl_xor(ss, m);
    float rn = rsqrtf(ss);
    ushort4 o;
    o.x = f2bf(v.x * rn); o.y = f2bf(v.y * rn); o.z = f2bf(v.z * rn); o.w = f2bf(v.w * rn);
    *(ushort4*)(dst + (size_t)row * D + lane * 4) = o;
}

// Mega kernel, grid (Q/128, NSPLIT+1).
// y==0: SQ path (64 sections x 128 questions, reg-direct MFMA).
// y>=1: QS q-tile 128 x n-range N/NSPLIT. Barrier-free K-loop: A-tile (128x256)
// staged ONCE in LDS (chunk-XOR swizzle c^=r&7, both sides), B fragments loaded
// global->reg per K-step (contiguous bf16x8/lane), no K-loop barriers at all.
__global__ __launch_bounds__(256, 2)
void qs_sq(const unsigned short* __restrict__ queb, const unsigned short* __restrict__ senb,
           const unsigned short* __restrict__ secb,
           const int* __restrict__ pidq, const int* __restrict__ pidn,
           const int* __restrict__ sidx, int Q, int N,
           float* __restrict__ partial, int* __restrict__ cnt, float* __restrict__ pos_s,
           float* __restrict__ sq_all, float* __restrict__ sq_pos, int* __restrict__ sq_m,
           float* __restrict__ simq) {
    __shared__ unsigned short As[128 * 256];
    __shared__ int pqs[128];
    __shared__ float sums[2][128];
    __shared__ int lcnt;
    __shared__ int lq[PBUF];
    __shared__ float lsv[PBUF];

    const int tid = threadIdx.x;
    const int lane = tid & 63;
    const int cl = lane & 15;
    const int g = lane >> 4;
    const int wid = tid >> 6;

    if (blockIdx.y == 0) {
        // ---------------- SQ path ----------------
        const int q0 = blockIdx.x * 128;
        const int qw = q0 + wid * 32;
        f32x4 acc[4][2];
        #pragma unroll
        for (int si = 0; si < 4; ++si)
            #pragma unroll
            for (int qi = 0; qi < 2; ++qi)
                acc[si][qi] = (f32x4){0.f, 0.f, 0.f, 0.f};
        const unsigned short* abase = secb + (size_t)cl * D + g * 8;
        const unsigned short* bbase = queb + (size_t)(qw + cl) * D + g * 8;
        #pragma unroll
        for (int kk = 0; kk < 8; ++kk) {
            const int k0 = kk * 32;
            bf16x8_t af[4], bq[2];
            #pragma unroll
            for (int si = 0; si < 4; ++si)
                af[si] = *(const bf16x8_t*)(abase + si * 16 * D + k0);
            #pragma unroll
            for (int qi = 0; qi < 2; ++qi)
                bq[qi] = *(const bf16x8_t*)(bbase + qi * 16 * D + k0);
            #pragma unroll
            for (int si = 0; si < 4; ++si)
                #pragma unroll
                for (int qi = 0; qi < 2; ++qi)
                    acc[si][qi] = __builtin_amdgcn_mfma_f32_16x16x32_bf16(af[si], bq[qi], acc[si][qi], 0, 0, 0);
        }
        int sidxv[2];
        sidxv[0] = sidx[qw + cl];
        sidxv[1] = sidx[qw + 16 + cl];
        #pragma unroll
        for (int si = 0; si < 4; ++si) {
            float pa[4] = {0.f, 0.f, 0.f, 0.f};
            #pragma unroll
            for (int qi = 0; qi < 2; ++qi) {
                #pragma unroll
                for (int j = 0; j < 4; ++j) {
                    int srow = si * 16 + g * 4 + j;
                    float sv = acc[si][qi][j] * INV_TAU;
                    float e = __expf(sv);
                    pa[j] += e;
                    if (sidxv[qi] == srow) {
                        int q = qw + qi * 16 + cl;
                        simq[q] = sv;
                        atomicAdd(&sq_pos[srow], e);
                        atomicAdd(&sq_m[srow], 1);
                    }
                }
            }
            #pragma unroll
            for (int j = 0; j < 4; ++j) {
                float a = pa[j];
                #pragma unroll
                for (int msk = 1; msk < 16; msk <<= 1) a += __shfl_xor(a, msk);
                if (cl == 0) atomicAdd(&sq_all[si * 16 + g * 4 + j], a);
            }
        }
        return;
    }

    // ---------------- QS path ----------------
    const int wr = wid >> 1, wc = wid & 1;
    const int q0 = blockIdx.x * 128;
    const int split = blockIdx.y - 1;
    const int n0base = split * (N / NSPLIT);
    const int niter = (N / NSPLIT) >> 7;

    if (tid < 128) pqs[tid] = pidq[q0 + tid];
    if (tid == 0) lcnt = 0;

    // Stage A once: 4096 chunks; thread handles cid = j*256 + tid.
    // r = j*8 + (tid>>5) (so r&7 = tid>>5, j-independent); c = tid&31.
    // Source pre-swizzled (c ^ r&7), LDS dest linear.
    {
        const unsigned short* asrc = queb + (size_t)(q0 + (tid >> 5)) * D
                                   + (((tid & 31) ^ (tid >> 5)) << 3);
        #pragma unroll
        for (int j = 0; j < 16; ++j)
            GLOAD16(asrc + j * 8 * D, &As[(j * 256 + wid * 64) * 8]);
    }
    __syncthreads();

    int pqr[16];
    #pragma unroll
    for (int m = 0; m < 4; ++m)
        #pragma unroll
        for (int j = 0; j < 4; ++j)
            pqr[m * 4 + j] = pqs[wr * 64 + m * 16 + g * 4 + j];

    float se[16];
    #pragma unroll
    for (int i = 0; i < 16; ++i) se[i] = 0.f;

    // A read bases: element offset = r*256 + ((4kk+g)^(cl&7))*8, r = wr*64+m*16+cl.
    int abase0 = (wr * 64 + cl) * 256;

    for (int ni = 0; ni < niter; ++ni) {
        const int n0 = n0base + ni * 128;
        const unsigned short* bp[4];
        #pragma unroll
        for (int n = 0; n < 4; ++n)
            bp[n] = senb + (size_t)(n0 + wc * 64 + n * 16 + cl) * D + g * 8;

        f32x4 acc[4][4];
        #pragma unroll
        for (int m = 0; m < 4; ++m)
            #pragma unroll
            for (int n = 0; n < 4; ++n)
                acc[m][n] = (f32x4){0.f, 0.f, 0.f, 0.f};

        #pragma unroll
        for (int kk = 0; kk < 8; ++kk) {
            const int ct = ((kk * 4 + g) ^ (cl & 7)) << 3;
            bf16x8_t af[4], bg[4];
            #pragma unroll
            for (int n = 0; n < 4; ++n)
                bg[n] = *(const bf16x8_t*)(bp[n] + kk * 32);
            #pragma unroll
            for (int m = 0; m < 4; ++m)
                af[m] = *(const bf16x8_t*)&As[abase0 + m * 4096 + ct];
            #pragma unroll
            for (int m = 0; m < 4; ++m)
                #pragma unroll
                for (int n = 0; n < 4; ++n)
                    acc[m][n] = __builtin_amdgcn_mfma_f32_16x16x32_bf16(af[m], bg[n], acc[m][n], 0, 0, 0);
        }

        // Epilogue: exp + reg-accumulated row sums + LDS positive capture.
        int pcol[4];
        #pragma unroll
        for (int n = 0; n < 4; ++n) pcol[n] = pidn[n0 + wc * 64 + n * 16 + cl];
        #pragma unroll
        for (int m = 0; m < 4; ++m) {
            #pragma unroll
            for (int n = 0; n < 4; ++n) {
                #pragma unroll
                for (int j = 0; j < 4; ++j) {
                    float s = acc[m][n][j] * INV_TAU;
                    float e = __expf(s);
                    se[m * 4 + j] += e;
                    if (pqr[m * 4 + j] == pcol[n]) {
                        int li = atomicAdd(&lcnt, 1);
                        if (li < PBUF) { lq[li] = q0 + wr * 64 + m * 16 + g * 4 + j; lsv[li] = s; }
                    }
                }
            }
        }
    }

    // Block reduction of row sums + partial store + capture drain.
    #pragma unroll
    for (int i = 0; i < 16; ++i) {
        float a = se[i];
        #pragma unroll
        for (int msk = 1; msk < 16; msk <<= 1) a += __shfl_xor(a, msk);
        if (cl == 0) sums[wc][wr * 64 + (i >> 2) * 16 + g * 4 + (i & 3)] = a;
    }
    __syncthreads();
    if (tid < 128)
        partial[(size_t)split * Q + q0 + tid] = sums[0][tid] + sums[1][tid];
    int nc = lcnt < PBUF ? lcnt : PBUF;
    for (int i = tid; i < nc; i += 256) {
        int q = lq[i];
        int idx = atomicAdd(&cnt[q], 1);
        if (idx < CAP) pos_s[(size_t)q * CAP + idx] = lsv[i];
    }
}

// Finish: wave per question. Reduces row partials, computes g + QS terms + SQ term.
__global__ __launch_bounds__(256)
void finish(const float* __restrict__ partial, int NB,
            const int* __restrict__ cnt, const float* __restrict__ pos_s,
            const int* __restrict__ sidx, const float* __restrict__ simq,
            const float* __restrict__ sq_all, const float* __restrict__ sq_pos,
            const int* __restrict__ sq_m,
            const int* __restrict__ npp, int Qn, int Ntot,
            float* __restrict__ bpart) {
    __shared__ float fred[4][4];
    const int tid = threadIdx.x, lane = tid & 63, wid = tid >> 6;
    const int q = blockIdx.x * 4 + wid;

    float Sa = 0.f;
    for (int nb = lane; nb < NB; nb += 64) Sa += partial[(size_t)nb * Qn + q];
    #pragma unroll
    for (int m = 1; m < 64; m <<= 1) Sa += __shfl_xor(Sa, m);

    int M = cnt[q];
    int mc = M < CAP ? M : CAP;
    float s = 0.f, e = 0.f;
    if (lane < mc) { s = pos_s[(size_t)q * CAP + lane]; e = __expf(s); }
    float Sp = e;
    #pragma unroll
    for (int m = 1; m < 64; m <<= 1) Sp += __shfl_xor(Sp, m);

    int Nn = Ntot - M;
    int P = npp[0];
    float eta_p = 1.0f / (float)(P > 1 ? P : 1);
    float eta_m = 1.0f - eta_p;
    float Mf = (float)(M > 1 ? M : 1);
    float Nnf = (float)(Nn > 1 ? Nn : 1);
    float gg = fmaxf(((Sa - Sp) / Nnf - eta_p * Sp / Mf) / eta_m, __expf(-INV_TAU));
    float c = (float)Nn * gg;

    float contrib = (lane < mc) ? (s - __logf(e + c)) : 0.f;
    #pragma unroll
    for (int m = 1; m < 64; m <<= 1) contrib += __shfl_xor(contrib, m);

    if (lane == 0) {
        float qs_num = 0.f, qs_cnt = 0.f, sq_num = 0.f, sq_cnt = 0.f;
        if (M > 0 && Nn > 0) { qs_num = contrib; qs_cnt = (float)M; }
        int sct = sidx[q];
        int Mq = sq_m[sct];
        if (Mq > 0 && (Qn - Mq) > 0) {
            float sv = simq[q];
            float sumneg = sq_all[sct] - sq_pos[sct];
            sq_num = sv - __logf(__expf(sv) + sumneg);
            sq_cnt = 1.f;
        }
        fred[wid][0] = qs_num; fred[wid][1] = qs_cnt;
        fred[wid][2] = sq_num; fred[wid][3] = sq_cnt;
    }
    __syncthreads();
    if (tid < 4) {
        float v = fred[0][tid] + fred[1][tid] + fred[2][tid] + fred[3][tid];
        bpart[(size_t)blockIdx.x * 4 + tid] = v;
    }
}

__global__ void combine2(const float* __restrict__ bpart, int nblk, float* __restrict__ out) {
    __shared__ float r2[4][4];
    const int tid = threadIdx.x, lane = tid & 63, wid = tid >> 6;
    float v[4] = {0.f, 0.f, 0.f, 0.f};
    for (int i = tid; i < nblk; i += 256) {
        #pragma unroll
        for (int c2 = 0; c2 < 4; ++c2) v[c2] += bpart[(size_t)i * 4 + c2];
    }
    #pragma unroll
    for (int m = 1; m < 64; m <<= 1)
        #pragma unroll
        for (int c2 = 0; c2 < 4; ++c2) v[c2] += __shfl_xor(v[c2], m);
    if (lane == 0) {
        #pragma unroll
        for (int c2 = 0; c2 < 4; ++c2) r2[wid][c2] = v[c2];
    }
    __syncthreads();
    if (tid == 0) {
        float qs_num = r2[0][0] + r2[1][0] + r2[2][0] + r2[3][0];
        float qs_cnt = r2[0][1] + r2[1][1] + r2[2][1] + r2[3][1];
        float sq_num = r2[0][2] + r2[1][2] + r2[2][2] + r2[3][2];
        float sq_cnt = r2[0][3] + r2[1][3] + r2[2][3] + r2[3][3];
        float qs = qs_cnt > 0.f ? -qs_num / qs_cnt : 0.f;
        float sq = sq_cnt > 0.f ? -sq_num / sq_cnt : 0.f;
        out[0] = qs + sq;
    }
}

extern "C" void kernel_launch(void* const* d_in, const int* in_sizes, int n_in,
                              void* d_out, int out_size, void* d_ws, size_t ws_size,
                              hipStream_t stream) {
    const float* sec = (const float*)d_in[1];
    const float* que = (const float*)d_in[2];
    const float* sen = (const float*)d_in[3];
    const int* pidq = (const int*)d_in[4];
    const int* sidx = (const int*)d_in[5];
    const int* pidn = (const int*)d_in[6];
    const int* npp = (const int*)d_in[7];
    const int S = in_sizes[1] / D;
    const int Q = in_sizes[2] / D;
    const int N = in_sizes[3] / D;
    const int FBLK = Q / 4;

    char* p = (char*)d_ws;
    unsigned short* queb = (unsigned short*)p; p += (size_t)Q * D * 2;
    unsigned short* senb = (unsigned short*)p; p += (size_t)N * D * 2;
    unsigned short* secb = (unsigned short*)p; p += (size_t)S * D * 2;
    float* simq = (float*)p; p += (size_t)Q * 4;
    float* pos_s = (float*)p; p += (size_t)Q * CAP * 4;
    float* partial = (float*)p; p += (size_t)NSPLIT * Q * 4;
    float* bpart = (float*)p; p += (size_t)FBLK * 4 * 4;
    char* z0 = p;
    int* cnt = (int*)p; p += (size_t)Q * 4;
    float* sq_all = (float*)p; p += (size_t)S * 4;
    float* sq_pos = (float*)p; p += (size_t)S * 4;
    int* sq_m = (int*)p; p += (size_t)S * 4;
    size_t zbytes = (size_t)(p - z0);

    hipMemsetAsync(z0, 0, zbytes, stream);
    norm_all<<<(Q + N + S + 3) / 4, 256, 0, stream>>>(que, sen, sec, queb, senb, secb, Q, N, S);
    qs_sq<<<dim3(Q / 128, NSPLIT + 1), 256, 0, stream>>>(queb, senb, secb, pidq, pidn, sidx,
                                                         Q, N, partial, cnt, pos_s,
                                                         sq_all, sq_pos, sq_m, simq);
    finish<<<FBLK, 256, 0, stream>>>(partial, NSPLIT, cnt, pos_s, sidx, simq,
                                     sq_all, sq_pos, sq_m, npp, Q, N, bpart);
    combine2<<<1, 256, 0, stream>>>(bpart, FBLK, (float*)d_out);
}

// Round 8
// 96.023 us; speedup vs baseline: 1.2866x; 1.2866x over previous
//
#include <hip/hip_runtime.h>
#include <hip/hip_bf16.h>
#include <math.h>

#define D 256
#define INV_TAU 20.0f
#define CAP 64
#define PBUF 128

typedef __attribute__((ext_vector_type(4))) float f32x4;
typedef __attribute__((ext_vector_type(8))) short bf16x8_t;

#define GLOAD16(gp, lp) \
    __builtin_amdgcn_global_load_lds((const __attribute__((address_space(1))) void*)(gp), \
                                     (__attribute__((address_space(3))) void*)(lp), 16, 0, 0)

__device__ __forceinline__ unsigned short f2bf(float f) {
    union { float f; unsigned u; } v; v.f = f;
    unsigned r = v.u + 0x7FFFu + ((v.u >> 16) & 1u);
    return (unsigned short)(r >> 16);
}

// Fused: L2-normalize every row of que/sen/sec into bf16. Wave per row.
__global__ void norm_all(const float* __restrict__ que, const float* __restrict__ sen,
                         const float* __restrict__ sec,
                         unsigned short* __restrict__ queb, unsigned short* __restrict__ senb,
                         unsigned short* __restrict__ secb, int Q, int N, int S) {
    int r = blockIdx.x * 4 + (threadIdx.x >> 6);
    int lane = threadIdx.x & 63;
    if (r >= Q + N + S) return;
    const float* src; unsigned short* dst; int row;
    if (r < Q) { src = que; dst = queb; row = r; }
    else if (r < Q + N) { src = sen; dst = senb; row = r - Q; }
    else { src = sec; dst = secb; row = r - Q - N; }
    const float4* p = (const float4*)(src + (size_t)row * D);
    float4 v = p[lane];
    float ss = v.x * v.x + v.y * v.y + v.z * v.z + v.w * v.w;
    #pragma unroll
    for (int m = 1; m < 64; m <<= 1) ss += __shfl_xor(ss, m);
    float rn = rsqrtf(ss);
    ushort4 o;
    o.x = f2bf(v.x * rn); o.y = f2bf(v.y * rn); o.z = f2bf(v.z * rn); o.w = f2bf(v.w * rn);
    *(ushort4*)(dst + (size_t)row * D + lane * 4) = o;
}

// Mega kernel, 1-D grid = 32 SQ blocks + 4096 QS blocks.
// QS mapping is XCD-aware: xcd = (bid-32)&7 owns a contiguous 16-n-tile slice so
// its private L2 holds senb slice (1MB) + queb (2MB); q-tile varies fastest.
// QS tile 128x128, BK=32 double-buffered, counted vmcnt, chunk swizzle c^=(r>>1)&3.
__global__ __launch_bounds__(256, 4)
void qs_sq(const unsigned short* __restrict__ queb, const unsigned short* __restrict__ senb,
           const unsigned short* __restrict__ secb,
           const int* __restrict__ pidq, const int* __restrict__ pidn,
           const int* __restrict__ sidx, int Q,
           float* __restrict__ partial, int* __restrict__ cnt, float* __restrict__ pos_s,
           float* __restrict__ sq_all, float* __restrict__ sq_pos, int* __restrict__ sq_m,
           float* __restrict__ simq) {
    __shared__ unsigned short As[2][128 * 32];
    __shared__ unsigned short Bs[2][128 * 32];
    __shared__ int pqs[128];
    __shared__ int pns[128];
    __shared__ float sums[2][128];
    __shared__ int lcnt;
    __shared__ int lq[PBUF];
    __shared__ float lsv[PBUF];

    const int tid = threadIdx.x;
    const int lane = tid & 63;
    const int cl = lane & 15;
    const int g = lane >> 4;
    const int wid = tid >> 6;
    const int bid = blockIdx.x;
    const int nsq = Q >> 7;   // 32 SQ blocks

    if (bid < nsq) {
        // ---------------- SQ path: 64 sections x 128 questions ----------------
        const int q0 = bid * 128;
        const int qw = q0 + wid * 32;
        f32x4 acc[4][2];
        #pragma unroll
        for (int si = 0; si < 4; ++si)
            #pragma unroll
            for (int qi = 0; qi < 2; ++qi)
                acc[si][qi] = (f32x4){0.f, 0.f, 0.f, 0.f};
        const unsigned short* abase = secb + (size_t)cl * D + g * 8;
        const unsigned short* bbase = queb + (size_t)(qw + cl) * D + g * 8;
        #pragma unroll
        for (int kk = 0; kk < 8; ++kk) {
            const int k0 = kk * 32;
            bf16x8_t af[4], bq[2];
            #pragma unroll
            for (int si = 0; si < 4; ++si)
                af[si] = *(const bf16x8_t*)(abase + si * 16 * D + k0);
            #pragma unroll
            for (int qi = 0; qi < 2; ++qi)
                bq[qi] = *(const bf16x8_t*)(bbase + qi * 16 * D + k0);
            #pragma unroll
            for (int si = 0; si < 4; ++si)
                #pragma unroll
                for (int qi = 0; qi < 2; ++qi)
                    acc[si][qi] = __builtin_amdgcn_mfma_f32_16x16x32_bf16(af[si], bq[qi], acc[si][qi], 0, 0, 0);
        }
        int sidxv[2];
        sidxv[0] = sidx[qw + cl];
        sidxv[1] = sidx[qw + 16 + cl];
        #pragma unroll
        for (int si = 0; si < 4; ++si) {
            float pa[4] = {0.f, 0.f, 0.f, 0.f};
            #pragma unroll
            for (int qi = 0; qi < 2; ++qi) {
                #pragma unroll
                for (int j = 0; j < 4; ++j) {
                    int srow = si * 16 + g * 4 + j;
                    float sv = acc[si][qi][j] * INV_TAU;
                    float e = __expf(sv);
                    pa[j] += e;
                    if (sidxv[qi] == srow) {
                        int q = qw + qi * 16 + cl;
                        simq[q] = sv;
                        atomicAdd(&sq_pos[srow], e);
                        atomicAdd(&sq_m[srow], 1);
                    }
                }
            }
            #pragma unroll
            for (int j = 0; j < 4; ++j) {
                float a = pa[j];
                #pragma unroll
                for (int msk = 1; msk < 16; msk <<= 1) a += __shfl_xor(a, msk);
                if (cl == 0) atomicAdd(&sq_all[si * 16 + g * 4 + j], a);
            }
        }
        return;
    }

    // ---------------- QS path ----------------
    // XCD-aware decomposition: 4096 blocks = 8 xcd-slices x (32 q-tiles x 16 n-tiles).
    const int qbid = bid - nsq;
    const int xcd = qbid & 7;
    const int loc = qbid >> 3;
    const int qt = loc & 31;          // q-tile varies fastest within an XCD
    const int nt = xcd * 16 + (loc >> 5);
    const int wr = wid >> 1, wc = wid & 1;
    const int n0 = nt * 128;
    const int q0 = qt * 128;

    if (tid < 128) pqs[tid] = pidq[q0 + tid];
    else           pns[tid - 128] = pidn[n0 + tid - 128];
    if (tid == 0) lcnt = 0;
    __syncthreads();   // pid visible + vmcnt drained before counted waits

    // Staging: tile = 128 rows x 32 el = 512 16B-chunks per matrix; thread covers
    // chunks cid = (2w+j)*64 + lane, j=0,1. Source pre-swizzled (c ^ (r>>1)&3),
    // LDS dest linear in cid.
    int cid0 = (2 * wid) * 64 + lane;
    int cid1 = (2 * wid + 1) * 64 + lane;
    int r0 = cid0 >> 2, c0 = cid0 & 3;
    int r1 = cid1 >> 2, c1 = cid1 & 3;
    const unsigned short* qa0 = queb + (size_t)(q0 + r0) * D + ((c0 ^ ((r0 >> 1) & 3)) << 3);
    const unsigned short* qa1 = queb + (size_t)(q0 + r1) * D + ((c1 ^ ((r1 >> 1) & 3)) << 3);
    const unsigned short* sb0 = senb + (size_t)(n0 + r0) * D + ((c0 ^ ((r0 >> 1) & 3)) << 3);
    const unsigned short* sb1 = senb + (size_t)(n0 + r1) * D + ((c1 ^ ((r1 >> 1) & 3)) << 3);
    const int ld0 = (2 * wid) * 512;       // wave-uniform LDS element base
    const int ld1 = (2 * wid + 1) * 512;

#define STAGE(buf, k0) do { \
    GLOAD16(qa0 + (k0), &As[buf][ld0]); \
    GLOAD16(qa1 + (k0), &As[buf][ld1]); \
    GLOAD16(sb0 + (k0), &Bs[buf][ld0]); \
    GLOAD16(sb1 + (k0), &Bs[buf][ld1]); \
} while (0)

    f32x4 acc[4][4];
    #pragma unroll
    for (int m = 0; m < 4; ++m)
        #pragma unroll
        for (int n = 0; n < 4; ++n)
            acc[m][n] = (f32x4){0.f, 0.f, 0.f, 0.f};

    // Read offsets (constant per lane): want global chunk (r, g); stored at c = g ^ ((r>>1)&3).
    int offA[4], offB[4];
    #pragma unroll
    for (int m = 0; m < 4; ++m) {
        int r = wr * 64 + m * 16 + cl;
        offA[m] = r * 32 + ((g ^ ((r >> 1) & 3)) << 3);
    }
    #pragma unroll
    for (int n = 0; n < 4; ++n) {
        int r = wc * 64 + n * 16 + cl;
        offB[n] = r * 32 + ((g ^ ((r >> 1) & 3)) << 3);
    }

    STAGE(0, 0);
    #pragma unroll
    for (int ks = 0; ks < 8; ++ks) {
        const int cur = ks & 1;
        if (ks < 7) {
            STAGE(cur ^ 1, (ks + 1) * 32);
            asm volatile("s_waitcnt vmcnt(4)" ::: "memory");
        } else {
            asm volatile("s_waitcnt vmcnt(0)" ::: "memory");
        }
        __builtin_amdgcn_s_barrier();
        bf16x8_t af[4], bg[4];
        #pragma unroll
        for (int m = 0; m < 4; ++m) af[m] = *(const bf16x8_t*)&As[cur][offA[m]];
        #pragma unroll
        for (int n = 0; n < 4; ++n) bg[n] = *(const bf16x8_t*)&Bs[cur][offB[n]];
        #pragma unroll
        for (int m = 0; m < 4; ++m)
            #pragma unroll
            for (int n = 0; n < 4; ++n)
                acc[m][n] = __builtin_amdgcn_mfma_f32_16x16x32_bf16(af[m], bg[n], acc[m][n], 0, 0, 0);
        if (ks < 7) __builtin_amdgcn_s_barrier();
    }
#undef STAGE

    // Epilogue: exp + per-row sums (block-local) + LDS positive capture.
    #pragma unroll
    for (int m = 0; m < 4; ++m) {
        float se[4] = {0.f, 0.f, 0.f, 0.f};
        int pqr[4];
        #pragma unroll
        for (int j = 0; j < 4; ++j) pqr[j] = pqs[wr * 64 + m * 16 + g * 4 + j];
        #pragma unroll
        for (int n = 0; n < 4; ++n) {
            const int pcol = pns[wc * 64 + n * 16 + cl];
            #pragma unroll
            for (int j = 0; j < 4; ++j) {
                float s = acc[m][n][j] * INV_TAU;
                float e = __expf(s);
                se[j] += e;
                if (pqr[j] == pcol) {
                    int li = atomicAdd(&lcnt, 1);
                    if (li < PBUF) { lq[li] = q0 + wr * 64 + m * 16 + g * 4 + j; lsv[li] = s; }
                }
            }
        }
        #pragma unroll
        for (int j = 0; j < 4; ++j) {
            float a = se[j];
            #pragma unroll
            for (int msk = 1; msk < 16; msk <<= 1) a += __shfl_xor(a, msk);
            if (cl == 0) sums[wc][wr * 64 + m * 16 + g * 4 + j] = a;
        }
    }
    __syncthreads();
    if (tid < 128)
        partial[(size_t)nt * Q + q0 + tid] = sums[0][tid] + sums[1][tid];
    int nc = lcnt < PBUF ? lcnt : PBUF;
    for (int i = tid; i < nc; i += 256) {
        int q = lq[i];
        int idx = atomicAdd(&cnt[q], 1);
        if (idx < CAP) pos_s[(size_t)q * CAP + idx] = lsv[i];
    }
}

// Finish: wave per question. Reduces row partials, computes g + QS terms + SQ term.
__global__ __launch_bounds__(256)
void finish(const float* __restrict__ partial, int NB,
            const int* __restrict__ cnt, const float* __restrict__ pos_s,
            const int* __restrict__ sidx, const float* __restrict__ simq,
            const float* __restrict__ sq_all, const float* __restrict__ sq_pos,
            const int* __restrict__ sq_m,
            const int* __restrict__ npp, int Qn, int Ntot,
            float* __restrict__ bpart) {
    __shared__ float fred[4][4];
    const int tid = threadIdx.x, lane = tid & 63, wid = tid >> 6;
    const int q = blockIdx.x * 4 + wid;

    float Sa = 0.f;
    for (int nb = lane; nb < NB; nb += 64) Sa += partial[(size_t)nb * Qn + q];
    #pragma unroll
    for (int m = 1; m < 64; m <<= 1) Sa += __shfl_xor(Sa, m);

    int M = cnt[q];
    int mc = M < CAP ? M : CAP;
    float s = 0.f, e = 0.f;
    if (lane < mc) { s = pos_s[(size_t)q * CAP + lane]; e = __expf(s); }
    float Sp = e;
    #pragma unroll
    for (int m = 1; m < 64; m <<= 1) Sp += __shfl_xor(Sp, m);

    int Nn = Ntot - M;
    int P = npp[0];
    float eta_p = 1.0f / (float)(P > 1 ? P : 1);
    float eta_m = 1.0f - eta_p;
    float Mf = (float)(M > 1 ? M : 1);
    float Nnf = (float)(Nn > 1 ? Nn : 1);
    float gg = fmaxf(((Sa - Sp) / Nnf - eta_p * Sp / Mf) / eta_m, __expf(-INV_TAU));
    float c = (float)Nn * gg;

    float contrib = (lane < mc) ? (s - __logf(e + c)) : 0.f;
    #pragma unroll
    for (int m = 1; m < 64; m <<= 1) contrib += __shfl_xor(contrib, m);

    if (lane == 0) {
        float qs_num = 0.f, qs_cnt = 0.f, sq_num = 0.f, sq_cnt = 0.f;
        if (M > 0 && Nn > 0) { qs_num = contrib; qs_cnt = (float)M; }
        int sct = sidx[q];
        int Mq = sq_m[sct];
        if (Mq > 0 && (Qn - Mq) > 0) {
            float sv = simq[q];
            float sumneg = sq_all[sct] - sq_pos[sct];
            sq_num = sv - __logf(__expf(sv) + sumneg);
            sq_cnt = 1.f;
        }
        fred[wid][0] = qs_num; fred[wid][1] = qs_cnt;
        fred[wid][2] = sq_num; fred[wid][3] = sq_cnt;
    }
    __syncthreads();
    if (tid < 4) {
        float v = fred[0][tid] + fred[1][tid] + fred[2][tid] + fred[3][tid];
        bpart[(size_t)blockIdx.x * 4 + tid] = v;
    }
}

__global__ void combine2(const float* __restrict__ bpart, int nblk, float* __restrict__ out) {
    __shared__ float r2[4][4];
    const int tid = threadIdx.x, lane = tid & 63, wid = tid >> 6;
    float v[4] = {0.f, 0.f, 0.f, 0.f};
    for (int i = tid; i < nblk; i += 256) {
        #pragma unroll
        for (int c2 = 0; c2 < 4; ++c2) v[c2] += bpart[(size_t)i * 4 + c2];
    }
    #pragma unroll
    for (int m = 1; m < 64; m <<= 1)
        #pragma unroll
        for (int c2 = 0; c2 < 4; ++c2) v[c2] += __shfl_xor(v[c2], m);
    if (lane == 0) {
        #pragma unroll
        for (int c2 = 0; c2 < 4; ++c2) r2[wid][c2] = v[c2];
    }
    __syncthreads();
    if (tid == 0) {
        float qs_num = r2[0][0] + r2[1][0] + r2[2][0] + r2[3][0];
        float qs_cnt = r2[0][1] + r2[1][1] + r2[2][1] + r2[3][1];
        float sq_num = r2[0][2] + r2[1][2] + r2[2][2] + r2[3][2];
        float sq_cnt = r2[0][3] + r2[1][3] + r2[2][3] + r2[3][3];
        float qs = qs_cnt > 0.f ? -qs_num / qs_cnt : 0.f;
        float sq = sq_cnt > 0.f ? -sq_num / sq_cnt : 0.f;
        out[0] = qs + sq;
    }
}

extern "C" void kernel_launch(void* const* d_in, const int* in_sizes, int n_in,
                              void* d_out, int out_size, void* d_ws, size_t ws_size,
                              hipStream_t stream) {
    const float* sec = (const float*)d_in[1];
    const float* que = (const float*)d_in[2];
    const float* sen = (const float*)d_in[3];
    const int* pidq = (const int*)d_in[4];
    const int* sidx = (const int*)d_in[5];
    const int* pidn = (const int*)d_in[6];
    const int* npp = (const int*)d_in[7];
    const int S = in_sizes[1] / D;
    const int Q = in_sizes[2] / D;
    const int N = in_sizes[3] / D;
    const int NB = N / 128;
    const int FBLK = Q / 4;

    char* p = (char*)d_ws;
    unsigned short* queb = (unsigned short*)p; p += (size_t)Q * D * 2;
    unsigned short* senb = (unsigned short*)p; p += (size_t)N * D * 2;
    unsigned short* secb = (unsigned short*)p; p += (size_t)S * D * 2;
    float* simq = (float*)p; p += (size_t)Q * 4;
    float* pos_s = (float*)p; p += (size_t)Q * CAP * 4;
    float* partial = (float*)p; p += (size_t)NB * Q * 4;
    float* bpart = (float*)p; p += (size_t)FBLK * 4 * 4;
    char* z0 = p;
    int* cnt = (int*)p; p += (size_t)Q * 4;
    float* sq_all = (float*)p; p += (size_t)S * 4;
    float* sq_pos = (float*)p; p += (size_t)S * 4;
    int* sq_m = (int*)p; p += (size_t)S * 4;
    size_t zbytes = (size_t)(p - z0);

    hipMemsetAsync(z0, 0, zbytes, stream);
    norm_all<<<(Q + N + S + 3) / 4, 256, 0, stream>>>(que, sen, sec, queb, senb, secb, Q, N, S);
    // 32 SQ blocks (bids 0..31, multiple of 8 keeps XCD alignment) + 32x128 QS blocks.
    qs_sq<<<Q / 128 + (Q / 128) * NB, 256, 0, stream>>>(queb, senb, secb, pidq, pidn, sidx, Q,
                                                        partial, cnt, pos_s,
                                                        sq_all, sq_pos, sq_m, simq);
    finish<<<FBLK, 256, 0, stream>>>(partial, NB, cnt, pos_s, sidx, simq,
                                     sq_all, sq_pos, sq_m, npp, Q, N, bpart);
    combine2<<<1, 256, 0, stream>>>(bpart, FBLK, (float*)d_out);
}